// Round 1
// 295.379 us; speedup vs baseline: 1.1163x; 1.1163x over previous
//
#include <hip/hip_runtime.h>
#include <hip/hip_bf16.h>
#include <math.h>

// Cosine attention, n=8, L=S=2048, d=v=64.
// out0 = softmax((q^·k^T)/8) @ V  [8,2048,64]; out1 = softmax scores [8,2048,2048]
// |score| <= 1/8 (unit vectors) -> exp in [0.88,1.13] -> no running max needed.
// Single-pass design: QK computed TRANSPOSED (mfma(K,Q) -> D[s][l]) so each lane
// owns 4 consecutive s for one l-row:
//   - mask load is one int4 per lane per chunk (prefetched 2 chunks ahead)
//   - exp'd scores stash as bf16x4 regs -> score epilogue = stash * inv, float4
//     stores; NO pass B (no mask re-read, no QK recompute).
// Mask arrives as int32 (harness materializes bool as int) — NOT bytes.

typedef __bf16 bf16x8 __attribute__((ext_vector_type(8)));
typedef __bf16 bf16x4 __attribute__((ext_vector_type(4)));
typedef float f32x4 __attribute__((ext_vector_type(4)));

#define NB 8
#define LL 2048
#define SS 2048
#define DD 64

// ---- prep 1: L2-normalize Q (fold 1/8) and K rows, cast to bf16 ----
// one wave per row; 4 rows per 256-thread block; rows 0..16383 = Q, 16384.. = K
__global__ __launch_bounds__(256) void prep_norm(const float* __restrict__ q,
                                                 const float* __restrict__ k,
                                                 __bf16* __restrict__ Qb,
                                                 __bf16* __restrict__ Kb) {
  int w = threadIdx.x >> 6, lane = threadIdx.x & 63;
  int r = blockIdx.x * 4 + w;
  const float* src;
  __bf16* dst;
  float extra;
  if (r < NB * LL) {
    src = q + (size_t)r * DD;
    dst = Qb + (size_t)r * DD;
    extra = 0.125f;  // fold 1/sqrt(64) into Q
  } else {
    int rk = r - NB * LL;
    src = k + (size_t)rk * DD;
    dst = Kb + (size_t)rk * DD;
    extra = 1.0f;
  }
  float x = src[lane];
  float ss = x * x;
  ss += __shfl_xor(ss, 1);
  ss += __shfl_xor(ss, 2);
  ss += __shfl_xor(ss, 4);
  ss += __shfl_xor(ss, 8);
  ss += __shfl_xor(ss, 16);
  ss += __shfl_xor(ss, 32);
  float nrm = sqrtf(ss);
  float sc = extra / fmaxf(nrm, 1e-12f);
  dst[lane] = (__bf16)(x * sc);
}

// ---- prep 2: V [n][s][v] f32 -> Vt [n][v][s] bf16 (64x64 LDS tiles) ----
__global__ __launch_bounds__(256) void prep_vt(const float* __restrict__ v,
                                               __bf16* __restrict__ Vt) {
  __shared__ __bf16 tile[64][72];
  int n = blockIdx.y;
  int s0 = blockIdx.x * 64;
  int t = threadIdx.x;
#pragma unroll
  for (int it = 0; it < 4; ++it) {
    int idx = t + it * 256;
    int s = idx >> 4, c = idx & 15;
    float4 f = *(const float4*)(v + ((size_t)(n * SS + s0 + s)) * DD + c * 4);
    tile[s][c * 4 + 0] = (__bf16)f.x;
    tile[s][c * 4 + 1] = (__bf16)f.y;
    tile[s][c * 4 + 2] = (__bf16)f.z;
    tile[s][c * 4 + 3] = (__bf16)f.w;
  }
  __syncthreads();
#pragma unroll
  for (int it = 0; it < 4; ++it) {
    int idx = t + it * 256;
    int vv = idx >> 4, c = idx & 15;
    bf16x4 o;
    o[0] = tile[c * 4 + 0][vv];
    o[1] = tile[c * 4 + 1][vv];
    o[2] = tile[c * 4 + 2][vv];
    o[3] = tile[c * 4 + 3][vv];
    *(bf16x4*)(Vt + ((size_t)(n * DD + vv)) * SS + s0 + c * 4) = o;
  }
}

// ---- main: 16 L-rows per block, 8 waves (512 thr), S streamed in 128-col chunks ----
// Wave w: QK for s-cols [w*16, w*16+16) of each chunk (transposed D[s][l]);
// PV split by (v-group = w&3, s-half = (w>>2)*64); end: pairwise acc reduce in LDS.
// Per-lane ownership after transposed QK: (l = l0+m16, s = sc + w*16 + quad*4 + r).
__global__ __launch_bounds__(512, 4) void attn_main(const __bf16* __restrict__ Qb,
                                                    const __bf16* __restrict__ Kb,
                                                    const __bf16* __restrict__ Vt,
                                                    const int* __restrict__ mask,
                                                    float* __restrict__ out_val,
                                                    float* __restrict__ out_score) {
  __shared__ __bf16 e_lds[2][16][136];   // E chunk, row = l (0..15), col = s-in-chunk
  __shared__ float rs_lds[8][16];        // per-wave row-sum partials
  __shared__ float acc_red[4][16][17];   // PV partial exchange (upper s-half waves)

  const int n = blockIdx.y;
  const int l0 = blockIdx.x * 16;
  const int t = threadIdx.x;
  const int w = t >> 6;
  const int lane = t & 63;
  const int m16 = lane & 15;
  const int quad = lane >> 4;
  const int vg = w & 3;            // PV v-group
  const int sh = (w >> 2) * 64;    // PV s-half within chunk

  // Q fragment (B operand of transposed QK): B[n=m16][k=quad*8+j] = Q[l0+m16][k]
  const __bf16* qrow = Qb + ((size_t)(n * LL + l0 + m16)) * DD;
  bf16x8 aq0 = *(const bf16x8*)(qrow + quad * 8);
  bf16x8 aq1 = *(const bf16x8*)(qrow + 32 + quad * 8);

  const __bf16* kbase = Kb + (size_t)n * SS * DD;
  const __bf16* vrow = Vt + ((size_t)(n * DD + vg * 16 + m16)) * SS + sh;
  // per-lane index into mask/out_score: row l = l0+m16, col base = w*16+quad*4
  const size_t mrow = ((size_t)(n * LL + l0 + m16)) * SS + w * 16 + quad * 4;

  f32x4 acc_o = {0.f, 0.f, 0.f, 0.f};
  float rsum = 0.f;
  bf16x4 stash[16];  // exp'd scores, 4 consecutive s per chunk (static idx -> regs)
  int4 mkb[2];       // mask prefetch, depth 2
  mkb[0] = *(const int4*)(mask + mrow);
  mkb[1] = *(const int4*)(mask + mrow + 128);

#pragma unroll
  for (int c = 0; c < 16; ++c) {
    const int sc = c * 128;
    // K fragment (A operand): A[m=m16][k] = K[sc + w*16 + m16][k]
    const __bf16* krow = kbase + (size_t)(sc + w * 16 + m16) * DD;
    bf16x8 kb0 = *(const bf16x8*)(krow + quad * 8);
    bf16x8 kb1 = *(const bf16x8*)(krow + 32 + quad * 8);
    // Vt frags for this chunk's PV, issued early (consumed after the barrier)
    bf16x8 bv0 = *(const bf16x8*)(vrow + sc + quad * 8);
    bf16x8 bv1 = *(const bf16x8*)(vrow + sc + 32 + quad * 8);
    // QK transposed: D[row=quad*4+r -> s][col=m16 -> l]
    f32x4 acc = {0.f, 0.f, 0.f, 0.f};
    acc = __builtin_amdgcn_mfma_f32_16x16x32_bf16(kb0, aq0, acc, 0, 0, 0);
    acc = __builtin_amdgcn_mfma_f32_16x16x32_bf16(kb1, aq1, acc, 0, 0, 0);
    const int4 mk = mkb[c & 1];
    if (c + 2 < 16) mkb[c & 1] = *(const int4*)(mask + mrow + (size_t)(c + 2) * 128);
    float e0 = mk.x ? __expf(acc[0]) : 0.f;
    float e1 = mk.y ? __expf(acc[1]) : 0.f;
    float e2 = mk.z ? __expf(acc[2]) : 0.f;
    float e3 = mk.w ? __expf(acc[3]) : 0.f;
    rsum += (e0 + e1) + (e2 + e3);
    bf16x4 sv;
    sv[0] = (__bf16)e0;
    sv[1] = (__bf16)e1;
    sv[2] = (__bf16)e2;
    sv[3] = (__bf16)e3;
    stash[c] = sv;
    *(bf16x4*)(&e_lds[c & 1][m16][w * 16 + quad * 4]) = sv;
    __syncthreads();
    // PV: A = E[l][s-half], B = Vt[v-group][s-half]
    bf16x8 ae0 = *(const bf16x8*)(&e_lds[c & 1][m16][sh + quad * 8]);
    bf16x8 ae1 = *(const bf16x8*)(&e_lds[c & 1][m16][sh + 32 + quad * 8]);
    acc_o = __builtin_amdgcn_mfma_f32_16x16x32_bf16(ae0, bv0, acc_o, 0, 0, 0);
    acc_o = __builtin_amdgcn_mfma_f32_16x16x32_bf16(ae1, bv1, acc_o, 0, 0, 0);
    // dbuf proof: e_lds[c&1] next written at chunk c+2, which is after barrier
    // c+1, which is after all reads of chunk c.
  }

  // rowsum: lane has partial for row l=m16 over its s slices; reduce quads, waves
  rsum += __shfl_xor(rsum, 16);
  rsum += __shfl_xor(rsum, 32);
  if (quad == 0) rs_lds[w][m16] = rsum;
  // upper s-half waves publish PV partials
  if (w >= 4) {
#pragma unroll
    for (int r = 0; r < 4; ++r) acc_red[vg][quad * 4 + r][m16] = acc_o[r];
  }
  __syncthreads();

  float tot = 0.f;
#pragma unroll
  for (int ww = 0; ww < 8; ++ww) tot += rs_lds[ww][m16];
  const float inv_s = 1.0f / tot;  // for score rows (l = l0+m16)

  // out_value: lower s-half waves combine pair partials; C/D rows are l=quad*4+r
  if (w < 4) {
#pragma unroll
    for (int r = 0; r < 4; ++r) {
      const int row = quad * 4 + r;
      float tr = 0.f;
#pragma unroll
      for (int ww = 0; ww < 8; ++ww) tr += rs_lds[ww][row];
      const float o = (acc_o[r] + acc_red[vg][row][m16]) / tr;
      out_val[((size_t)(n * LL + l0 + row)) * DD + vg * 16 + m16] = o;
    }
  }

  // score epilogue: replay stash * inv, coalesced float4 stores (only P write)
  float* orow = out_score + mrow;
#pragma unroll
  for (int c = 0; c < 16; ++c) {
    float4 o;
    o.x = (float)stash[c][0] * inv_s;
    o.y = (float)stash[c][1] * inv_s;
    o.z = (float)stash[c][2] * inv_s;
    o.w = (float)stash[c][3] * inv_s;
    *(float4*)(orow + (size_t)c * 128) = o;
  }
}

extern "C" void kernel_launch(void* const* d_in, const int* in_sizes, int n_in,
                              void* d_out, int out_size, void* d_ws, size_t ws_size,
                              hipStream_t stream) {
  const float* q = (const float*)d_in[0];
  const float* k = (const float*)d_in[1];
  const float* v = (const float*)d_in[2];
  const int* mask = (const int*)d_in[3];  // harness materializes bool as int32

  float* out_val = (float*)d_out;                       // [8,2048,64]
  float* out_score = out_val + (size_t)NB * LL * DD;    // [8,2048,2048]

  __bf16* Qb = (__bf16*)d_ws;                  // 2 MB
  __bf16* Kb = Qb + (size_t)NB * LL * DD;      // 2 MB
  __bf16* Vt = Kb + (size_t)NB * SS * DD;      // 2 MB (transposed [n][v][s])

  prep_norm<<<dim3((NB * LL * 2) / 4), dim3(256), 0, stream>>>(q, k, Qb, Kb);
  prep_vt<<<dim3(SS / 64, NB), dim3(256), 0, stream>>>(v, Vt);
  attn_main<<<dim3(LL / 16, NB), dim3(512), 0, stream>>>(Qb, Kb, Vt, mask, out_val, out_score);
}